// Round 6
// baseline (572.173 us; speedup 1.0000x reference)
//
#include <hip/hip_runtime.h>
#include <stdint.h>

#define NB 16
#define NM 64
#define NS 256
#define NE 256
#define NH 256

// ---------------- threefry2x32 (jax-exact) ----------------
__device__ __forceinline__ uint32_t rotl32(uint32_t v, int d) { return (v << d) | (v >> (32 - d)); }

__device__ __forceinline__ void threefry(uint32_t k0, uint32_t k1,
                                         uint32_t x0, uint32_t x1,
                                         uint32_t& o0, uint32_t& o1) {
  uint32_t ks2 = k0 ^ k1 ^ 0x1BD11BDAu;
#define TFR(r) { x0 += x1; x1 = rotl32(x1, r); x1 ^= x0; }
  x0 += k0; x1 += k1;
  TFR(13) TFR(15) TFR(26) TFR(6)
  x0 += k1;  x1 += ks2 + 1u;
  TFR(17) TFR(29) TFR(16) TFR(24)
  x0 += ks2; x1 += k0 + 2u;
  TFR(13) TFR(15) TFR(26) TFR(6)
  x0 += k0;  x1 += k1 + 3u;
  TFR(17) TFR(29) TFR(16) TFR(24)
  x0 += k1;  x1 += ks2 + 4u;
  TFR(13) TFR(15) TFR(26) TFR(6)
  x0 += ks2; x1 += k0 + 5u;
#undef TFR
  o0 = x0; o1 = x1;
}

// uniform->gumbel exactly as jax: u01 = bitcast((bits>>9)|0x3f800000)-1; u=max(u01,tiny); g=-log(-log(u))
__device__ __forceinline__ float gumbel_from_bits(uint32_t bits) {
  float u = __uint_as_float((bits >> 9) | 0x3f800000u) - 1.0f;
  u = fmaxf(u, 1.17549435e-38f);
  return -logf(-logf(u));
}

// g[b][i][s] — jax_threefry_partitionable=True chain:
//   bkeys[b] = threefry((0,42),(0,b)); fkey = threefry(bkey,(0,i));
//   bits[s] = o0 ^ o1 of threefry(fkey,(0,s))
__global__ void gumbel_kernel(float* __restrict__ g) {
  const int blk = blockIdx.x;       // b*64 + i
  const int b = blk >> 6;
  const int i = blk & 63;
  const int s = threadIdx.x;        // 0..255
  uint32_t kb0, kb1, f0, f1, r0, r1;
  threefry(0u, 42u, 0u, (uint32_t)b, kb0, kb1);
  threefry(kb0, kb1, 0u, (uint32_t)i, f0, f1);
  threefry(f0, f1, 0u, (uint32_t)s, r0, r1);
  g[(blk << 8) + s] = gumbel_from_bits(r0 ^ r1);
}

// ---------------- per-batch prep: qbase = (h_bar+bv)@Wq, q0W = (h_bar+bv+init_w@Wv)@Wq ----------------
__global__ void prep_kernel(const float* __restrict__ emb,
                            const float* __restrict__ init_w,
                            const float* __restrict__ Whc,
                            const float* __restrict__ bhc,
                            const float* __restrict__ Wv,
                            const float* __restrict__ bv,
                            const float* __restrict__ Wq,
                            float* __restrict__ qbase,
                            float* __restrict__ q0W) {
  const int b = blockIdx.x, t = threadIdx.x;
  __shared__ float mean_s[NE];
  __shared__ float hbpb[NE];
  __shared__ float iwv[NE];
  const float* eb = emb + (size_t)b * NS * NE;
  float acc = 0.f;
  for (int s = 0; s < NS; ++s) acc += eb[s * NE + t];
  mean_s[t] = acc * (1.0f / NS);
  __syncthreads();
  float h = bhc[t];
  for (int j = 0; j < NE; ++j) h = fmaf(mean_s[j], Whc[j * NE + t], h);
  hbpb[t] = h + bv[t];
  float a2 = 0.f;
  for (int j = 0; j < 2 * NE; ++j) a2 = fmaf(init_w[j], Wv[j * NE + t], a2);
  iwv[t] = a2;
  __syncthreads();
  float qb = 0.f, q0 = 0.f;
  for (int e = 0; e < NE; ++e) {
    float w = Wq[e * NH + t];
    qb = fmaf(hbpb[e], w, qb);
    q0 = fmaf(hbpb[e] + iwv[e], w, q0);
  }
  qbase[b * NH + t] = qb;
  q0W[b * NH + t] = q0;
}

// ---------------- generic row-block GEMM: C[row][h] = sum_e A[row][e]*W[e][h], 16 rows/block ----------------
__global__ void mm_kernel(const float* __restrict__ A,
                          const float* __restrict__ W,
                          float* __restrict__ C) {
  const int t = threadIdx.x;
  const int hq = (t & 63) * 4;
  const int r0 = (t >> 6) * 4;
  const int rowbase = blockIdx.x * 16;
  float acc[4][4] = {};
  #pragma unroll 2
  for (int e = 0; e < NE; ++e) {
    float4 w = *(const float4*)(W + e * NH + hq);
    #pragma unroll
    for (int r = 0; r < 4; ++r) {
      float a = A[(size_t)(rowbase + r0 + r) * NE + e];   // wave-uniform -> scalar path
      acc[r][0] = fmaf(a, w.x, acc[r][0]);
      acc[r][1] = fmaf(a, w.y, acc[r][1]);
      acc[r][2] = fmaf(a, w.z, acc[r][2]);
      acc[r][3] = fmaf(a, w.w, acc[r][3]);
    }
  }
  #pragma unroll
  for (int r = 0; r < 4; ++r)
    *(float4*)(C + (size_t)(rowbase + r0 + r) * NH + hq) =
        make_float4(acc[r][0], acc[r][1], acc[r][2], acc[r][3]);
}

// fast tanh: (e^{2x}-1)/(e^{2x}+1); x<=40 clamp prevents inf/inf; negative side exact (-1)
__device__ __forceinline__ float tanh_fast(float x) {
  float t = __expf(fminf(x, 40.f) * 2.0f);
  return (t - 1.f) * __builtin_amdgcn_rcpf(t + 1.f);
}

// padded LDS index for 4x64 chunked vectors: chunk hc at 68-float stride
// -> float4 read addrs of the 4 hc lanes land on banks {4j..},{4j+4..},{4j+8..},{4j+12..}: conflict-free
#define PIDX(h) (((h) >> 6) * 68 + ((h) & 63))

// ---------------- sequential decode: 1 block per batch item ----------------
// Block=1024 forces 1 block/CU (4 waves/SIMD) -> VGPR cap 128 regardless of bounds.
// R5 lesson: compiler REMATERIALIZES the kp4 loads (const __restrict__ source) instead of
// keeping them live -> 256KB/block/step re-read from L2. The inline-asm "+v" barrier below
// makes each loaded value an opaque register def so the allocator must keep kp4 resident.
__global__ __launch_bounds__(1024, 4) void decode_kernel(
    const float* __restrict__ emb,
    const float* __restrict__ node,
    const float* __restrict__ costs,
    const float* __restrict__ Wv,
    const float* __restrict__ Wq,
    const float* __restrict__ vptr,
    const float* __restrict__ g_g,
    const float* __restrict__ kp_g,
    const float* __restrict__ QB_g,
    const float* __restrict__ qbase_g,
    const float* __restrict__ q0W_g,
    float* __restrict__ out) {
  const int b = blockIdx.x;
  const int tid = threadIdx.x;
  const int s = tid >> 2;
  const int hc = tid & 3;

  __shared__ float qWp[4 * 68];
  __shared__ float vpp[4 * 68];
  __shared__ float lg_s[NS];
  __shared__ float val_s[NS];
  __shared__ float red_v[4];
  __shared__ int   red_i[4];
  __shared__ float red_ml[4];
  __shared__ float red_e[4];
  __shared__ int   bc_idx;
  __shared__ int   idx_hist[NM];
  __shared__ float er[NE];
  __shared__ float Ts[NE];

  // each thread holds its 64 k_proj values in registers for the whole decode
  float4 kp4[16];
  {
    const float4* kpp = (const float4*)(kp_g + ((size_t)b * NS + s) * NH + hc * 64);
    #pragma unroll
    for (int j = 0; j < 16; ++j) kp4[j] = kpp[j];
  }
  // force register residency: make each component an opaque asm-defined value
  // (kills load-rematerialization; see R5 post-mortem)
  {
    float* kpf = reinterpret_cast<float*>(kp4);
    #pragma unroll
    for (int j = 0; j < 64; ++j) asm volatile("" : "+v"(kpf[j]));
  }
  if (tid < NH) {
    vpp[PIDX(tid)] = vptr[tid];
    qWp[PIDX(tid)] = q0W_g[b * NH + tid];
  }
  float qb_reg = (tid < NH) ? qbase_g[b * NH + tid] : 0.f;

  int m = 0;           // this thread's s masked?
  float logp = 0.f;    // thread 0 only
  const float* gb = g_g + (size_t)b * NM * NS;

  __syncthreads();

  for (int i = 0; i < NM; ++i) {
    // ---- u[s] = sum_h tanh(qW[h]+kp[s][h]) * vptr[h] ----
    if (!m) {
      const float4* q4 = (const float4*)(qWp + hc * 68);
      const float4* v4 = (const float4*)(vpp + hc * 68);
      float u = 0.f;
      #pragma unroll
      for (int j = 0; j < 16; ++j) {
        float4 q = q4[j], v = v4[j], k = kp4[j];
        u = fmaf(tanh_fast(q.x + k.x), v.x, u);
        u = fmaf(tanh_fast(q.y + k.y), v.y, u);
        u = fmaf(tanh_fast(q.z + k.z), v.z, u);
        u = fmaf(tanh_fast(q.w + k.w), v.w, u);
      }
      u += __shfl_xor(u, 1);
      u += __shfl_xor(u, 2);
      if (hc == 0) {
        float lg = 10.f * tanhf(u);
        lg_s[s] = lg;
        val_s[s] = lg + gb[i * NS + s];
      }
    }
    __syncthreads();                                    // sync1: lg/val ready

    // ---- fused per-wave: argmax(val) [first-index tiebreak], max(lg), sum exp(lg - ml_wave) ----
    if (tid < NS) {
      float lgl = lg_s[tid];
      float v = val_s[tid]; int vi = tid; float ml = lgl;
      #pragma unroll
      for (int off = 1; off < 64; off <<= 1) {
        float ov = __shfl_xor(v, off);
        int   oi = __shfl_xor(vi, off);
        bool take = (ov > v) || (ov == v && oi < vi);
        v  = take ? ov : v;
        vi = take ? oi : vi;
        ml = fmaxf(ml, __shfl_xor(ml, off));
      }
      float e = __expf(lgl - ml);                       // ml = wave max (butterfly -> all lanes)
      #pragma unroll
      for (int off = 1; off < 64; off <<= 1) e += __shfl_xor(e, off);
      if ((tid & 63) == 0) {
        red_v[tid >> 6] = v; red_i[tid >> 6] = vi;
        red_ml[tid >> 6] = ml; red_e[tid >> 6] = e;
      }
    }
    __syncthreads();                                    // sync2: wave partials ready

    if (tid == 0) {
      float bvv = red_v[0]; int bii = red_i[0]; float ml = red_ml[0];
      #pragma unroll
      for (int w = 1; w < 4; ++w) {
        if (red_v[w] > bvv || (red_v[w] == bvv && red_i[w] < bii)) { bvv = red_v[w]; bii = red_i[w]; }
        ml = fmaxf(ml, red_ml[w]);
      }
      float sum = 0.f;
      #pragma unroll
      for (int w = 0; w < 4; ++w) sum += red_e[w] * __expf(red_ml[w] - ml);
      logp += lg_s[bii] - (ml + logf(sum));
      bc_idx = bii;
      idx_hist[i] = bii;
      out[2 * NB + b * NM + i] = (float)bii;
    }
    __syncthreads();                                    // sync3: idx broadcast

    const int idx = bc_idx;
    // mask whole 4-node cell of idx; write the -1e9 sentinel exactly once
    if (!m && (s >> 2) == (idx >> 2)) {
      m = 1;
      if (hc == 0) { lg_s[s] = -1e9f; val_s[s] = -1e9f; }
    }

    // ---- one-time after step 0: fold Qinit = (emb[idx0]@Wv_top)@Wq into qbase ----
    if (i == 0) {
      if (tid < NE) er[tid] = emb[((size_t)b * NS + idx) * NE + tid];
      __syncthreads();
      if (tid < NE) {
        float tv = 0.f;
        #pragma unroll 4
        for (int j = 0; j < NE; ++j) tv = fmaf(er[j], Wv[j * NE + tid], tv);
        Ts[tid] = tv;
      }
      __syncthreads();
      if (tid < NE) {
        float qi = 0.f;
        #pragma unroll 4
        for (int e2 = 0; e2 < NE; ++e2) qi = fmaf(Ts[e2], Wq[e2 * NH + tid], qi);
        qb_reg += qi;
      }
    }

    // ---- next step's qW = qbase + Qinit + QB[idx] ----
    if (tid < NH) qWp[PIDX(tid)] = qb_reg + QB_g[((size_t)b * NS + idx) * NH + tid];
    __syncthreads();                                    // sync4: qW ready for next step
  }

  if (tid == 0) out[b] = logp;

  // ---- deferred reward: one wave, all 63 transition terms in parallel ----
  if (tid < 64) {
    float term = 0.f;
    if (tid > 0) {
      int id = idx_hist[tid];
      int pv = idx_hist[tid - 1];
      float dx = node[((size_t)b * NS + id) * 4 + 0] - node[((size_t)b * NS + pv) * 4 + 2];
      float dy = node[((size_t)b * NS + id) * 4 + 1] - node[((size_t)b * NS + pv) * 4 + 3];
      term = sqrtf(dx * dx + dy * dy) + costs[(size_t)b * NS + pv] + costs[(size_t)b * NS + id];
    }
    #pragma unroll
    for (int off = 1; off < 64; off <<= 1) term += __shfl_xor(term, off);
    if (tid == 0) out[NB + b] = term;
  }
}

extern "C" void kernel_launch(void* const* d_in, const int* in_sizes, int n_in,
                              void* d_out, int out_size, void* d_ws, size_t ws_size,
                              hipStream_t stream) {
  const float* emb    = (const float*)d_in[0];
  const float* node   = (const float*)d_in[1];
  // d_in[2] maze (unused), d_in[3] num_cell (constant 64)
  const float* costs  = (const float*)d_in[4];
  const float* init_w = (const float*)d_in[5];
  const float* Whc    = (const float*)d_in[6];
  const float* bhc    = (const float*)d_in[7];
  const float* Wv     = (const float*)d_in[8];
  const float* bv     = (const float*)d_in[9];
  const float* Wq     = (const float*)d_in[10];
  const float* Wk     = (const float*)d_in[11];
  const float* vptr   = (const float*)d_in[12];
  float* out = (float*)d_out;

  float* ws    = (float*)d_ws;
  float* g     = ws;                       // 16*64*256      = 262144
  float* kp    = g + NB * NM * NS;         // 16*256*256     = 1048576
  float* QB    = kp + (size_t)NB * NS * NH;
  float* tmpB  = QB + (size_t)NB * NS * NH;
  float* qbase = tmpB + (size_t)NB * NS * NE;
  float* q0W   = qbase + NB * NH;          // total ~13.1 MB of ws

  gumbel_kernel<<<NB * NM, 256, 0, stream>>>(g);
  prep_kernel<<<NB, NE, 0, stream>>>(emb, init_w, Whc, bhc, Wv, bv, Wq, qbase, q0W);
  mm_kernel<<<NB * NS / 16, 256, 0, stream>>>(emb, Wk, kp);               // k_proj
  mm_kernel<<<NB * NS / 16, 256, 0, stream>>>(emb, Wv + NE * NE, tmpB);   // emb @ Wv_bot
  mm_kernel<<<NB * NS / 16, 256, 0, stream>>>(tmpB, Wq, QB);              // (emb@Wv_bot)@Wq
  decode_kernel<<<NB, 1024, 0, stream>>>(emb, node, costs, Wv, Wq, vptr,
                                         g, kp, QB, qbase, q0W, out);
}

// Round 7
// 521.126 us; speedup vs baseline: 1.0980x; 1.0980x over previous
//
#include <hip/hip_runtime.h>
#include <stdint.h>

#define NB 16
#define NM 64
#define NS 256
#define NE 256
#define NH 256

// ---------------- threefry2x32 (jax-exact) ----------------
__device__ __forceinline__ uint32_t rotl32(uint32_t v, int d) { return (v << d) | (v >> (32 - d)); }

__device__ __forceinline__ void threefry(uint32_t k0, uint32_t k1,
                                         uint32_t x0, uint32_t x1,
                                         uint32_t& o0, uint32_t& o1) {
  uint32_t ks2 = k0 ^ k1 ^ 0x1BD11BDAu;
#define TFR(r) { x0 += x1; x1 = rotl32(x1, r); x1 ^= x0; }
  x0 += k0; x1 += k1;
  TFR(13) TFR(15) TFR(26) TFR(6)
  x0 += k1;  x1 += ks2 + 1u;
  TFR(17) TFR(29) TFR(16) TFR(24)
  x0 += ks2; x1 += k0 + 2u;
  TFR(13) TFR(15) TFR(26) TFR(6)
  x0 += k0;  x1 += k1 + 3u;
  TFR(17) TFR(29) TFR(16) TFR(24)
  x0 += k1;  x1 += ks2 + 4u;
  TFR(13) TFR(15) TFR(26) TFR(6)
  x0 += ks2; x1 += k0 + 5u;
#undef TFR
  o0 = x0; o1 = x1;
}

// uniform->gumbel exactly as jax: u01 = bitcast((bits>>9)|0x3f800000)-1; u=max(u01,tiny); g=-log(-log(u))
__device__ __forceinline__ float gumbel_from_bits(uint32_t bits) {
  float u = __uint_as_float((bits >> 9) | 0x3f800000u) - 1.0f;
  u = fmaxf(u, 1.17549435e-38f);
  return -logf(-logf(u));
}

// g[b][i][s] — jax_threefry_partitionable=True chain:
//   bkeys[b] = threefry((0,42),(0,b)); fkey = threefry(bkey,(0,i));
//   bits[s] = o0 ^ o1 of threefry(fkey,(0,s))
__global__ void gumbel_kernel(float* __restrict__ g) {
  const int blk = blockIdx.x;       // b*64 + i
  const int b = blk >> 6;
  const int i = blk & 63;
  const int s = threadIdx.x;        // 0..255
  uint32_t kb0, kb1, f0, f1, r0, r1;
  threefry(0u, 42u, 0u, (uint32_t)b, kb0, kb1);
  threefry(kb0, kb1, 0u, (uint32_t)i, f0, f1);
  threefry(f0, f1, 0u, (uint32_t)s, r0, r1);
  g[(blk << 8) + s] = gumbel_from_bits(r0 ^ r1);
}

// ---------------- per-batch prep: qbase = (h_bar+bv)@Wq, q0W = (h_bar+bv+init_w@Wv)@Wq ----------------
__global__ void prep_kernel(const float* __restrict__ emb,
                            const float* __restrict__ init_w,
                            const float* __restrict__ Whc,
                            const float* __restrict__ bhc,
                            const float* __restrict__ Wv,
                            const float* __restrict__ bv,
                            const float* __restrict__ Wq,
                            float* __restrict__ qbase,
                            float* __restrict__ q0W) {
  const int b = blockIdx.x, t = threadIdx.x;
  __shared__ float mean_s[NE];
  __shared__ float hbpb[NE];
  __shared__ float iwv[NE];
  const float* eb = emb + (size_t)b * NS * NE;
  float acc = 0.f;
  for (int s = 0; s < NS; ++s) acc += eb[s * NE + t];
  mean_s[t] = acc * (1.0f / NS);
  __syncthreads();
  float h = bhc[t];
  for (int j = 0; j < NE; ++j) h = fmaf(mean_s[j], Whc[j * NE + t], h);
  hbpb[t] = h + bv[t];
  float a2 = 0.f;
  for (int j = 0; j < 2 * NE; ++j) a2 = fmaf(init_w[j], Wv[j * NE + t], a2);
  iwv[t] = a2;
  __syncthreads();
  float qb = 0.f, q0 = 0.f;
  for (int e = 0; e < NE; ++e) {
    float w = Wq[e * NH + t];
    qb = fmaf(hbpb[e], w, qb);
    q0 = fmaf(hbpb[e] + iwv[e], w, q0);
  }
  qbase[b * NH + t] = qb;
  q0W[b * NH + t] = q0;
}

// ---------------- generic row-block GEMM: C[row][h] = sum_e A[row][e]*W[e][h], 16 rows/block ----------------
__global__ void mm_kernel(const float* __restrict__ A,
                          const float* __restrict__ W,
                          float* __restrict__ C) {
  const int t = threadIdx.x;
  const int hq = (t & 63) * 4;
  const int r0 = (t >> 6) * 4;
  const int rowbase = blockIdx.x * 16;
  float acc[4][4] = {};
  #pragma unroll 2
  for (int e = 0; e < NE; ++e) {
    float4 w = *(const float4*)(W + e * NH + hq);
    #pragma unroll
    for (int r = 0; r < 4; ++r) {
      float a = A[(size_t)(rowbase + r0 + r) * NE + e];   // wave-uniform -> scalar path
      acc[r][0] = fmaf(a, w.x, acc[r][0]);
      acc[r][1] = fmaf(a, w.y, acc[r][1]);
      acc[r][2] = fmaf(a, w.z, acc[r][2]);
      acc[r][3] = fmaf(a, w.w, acc[r][3]);
    }
  }
  #pragma unroll
  for (int r = 0; r < 4; ++r)
    *(float4*)(C + (size_t)(rowbase + r0 + r) * NH + hq) =
        make_float4(acc[r][0], acc[r][1], acc[r][2], acc[r][3]);
}

// padded LDS index: 8 chunks of 32 floats at stride 36
// -> b128 reads: 8 distinct chunk bases land on disjoint 4-bank groups (4*(hc+j) mod 32): conflict-free
// -> 64-lane float writes: 2 lanes/bank (free per m136)
#define PIDX(h) (((h) >> 5) * 36 + ((h) & 31))

// ---------------- sequential decode: 1 block per batch item ----------------
// Layout: thread t handles s-pair {2*(t>>3), 2*(t>>3)+1} x 32-h chunk (t&7).
//   - q/v LDS reads shared across the 2 s -> LDS traffic halved vs 1-s/thread
//   - lean tanh: sum vp*tanh = Vsum - 2*sum vp*rcp(e^{2x}+1); kp/qW pre-scaled by 2,
//     LDS holds -2*vp  -> 5 VALU + 2 trans per element
//   - 3 barriers/step: all-thread combine of wave partials (no thread0-broadcast barrier);
//     mask sentinel deferred to next step's compute phase (no lg_s read/write race)
__global__ __launch_bounds__(1024, 4) void decode_kernel(
    const float* __restrict__ emb,
    const float* __restrict__ node,
    const float* __restrict__ costs,
    const float* __restrict__ Wv,
    const float* __restrict__ Wq,
    const float* __restrict__ vptr,
    const float* __restrict__ g_g,
    const float* __restrict__ kp_g,
    const float* __restrict__ QB_g,
    const float* __restrict__ qbase_g,
    const float* __restrict__ q0W_g,
    float* __restrict__ out) {
  const int b = blockIdx.x;
  const int tid = threadIdx.x;
  const int hc = tid & 7;          // 32-float h-chunk
  const int pr = tid >> 3;         // s-pair index 0..127
  const int s0 = pr * 2, s1 = s0 + 1;

  __shared__ float qWp[8 * 36];
  __shared__ float vpp[8 * 36];
  __shared__ float lg_s[NS];
  __shared__ float val_s[NS];
  __shared__ float red_v[4];
  __shared__ int   red_i[4];
  __shared__ float red_ml[4];
  __shared__ float red_e[4];
  __shared__ int   idx_hist[NM];
  __shared__ float er[NE];
  __shared__ float Ts[NE];

  // kp registers: 2 s x 32 h = 64 floats, pre-scaled by 2 (for e^{2x} via __expf)
  float4 kp0[8], kp1[8];
  {
    const float4* p0 = (const float4*)(kp_g + ((size_t)b * NS + s0) * NH + hc * 32);
    const float4* p1 = (const float4*)(kp_g + ((size_t)b * NS + s1) * NH + hc * 32);
    #pragma unroll
    for (int j = 0; j < 8; ++j) {
      float4 a = p0[j], c = p1[j];
      kp0[j] = make_float4(2.f * a.x, 2.f * a.y, 2.f * a.z, 2.f * a.w);
      kp1[j] = make_float4(2.f * c.x, 2.f * c.y, 2.f * c.z, 2.f * c.w);
    }
  }
  // Vsum over this thread's 32 raw vp values
  float Vsum = 0.f;
  {
    const float4* vv = (const float4*)(vptr + hc * 32);
    #pragma unroll
    for (int j = 0; j < 8; ++j) { float4 v = vv[j]; Vsum += (v.x + v.y) + (v.z + v.w); }
  }
  if (tid < NH) {
    vpp[PIDX(tid)] = -2.0f * vptr[tid];
    qWp[PIDX(tid)] = 2.0f * q0W_g[b * NH + tid];
  }
  float qb_reg = (tid < NH) ? 2.0f * qbase_g[b * NH + tid] : 0.f;

  int m = 0, pend = 0;
  float logp = 0.f;                 // thread 0 only
  const float* gb = g_g + (size_t)b * NM * NS;

  __syncthreads();

  for (int i = 0; i < NM; ++i) {
    // ---- phase A: sentinel for newly-masked cell, else u = vp . tanh(qW+kp) ----
    if (pend) {
      pend = 0;
      if (hc == 0) {
        lg_s[s0] = -1e9f; val_s[s0] = -1e9f;
        lg_s[s1] = -1e9f; val_s[s1] = -1e9f;
      }
    } else if (!m) {
      float2 g01 = make_float2(0.f, 0.f);
      if (hc == 0) g01 = *(const float2*)(gb + i * NS + s0);   // prefetch, used after tanh loop
      const float4* q4 = (const float4*)(qWp + hc * 36);
      const float4* v4 = (const float4*)(vpp + hc * 36);
      float a0 = 0.f, a1 = 0.f;
      #pragma unroll
      for (int j = 0; j < 8; ++j) {
        float4 q = q4[j], v = v4[j], k = kp0[j], l = kp1[j];
        {
          float y = fminf(q.x + k.x, 88.f), t = __expf(y);
          a0 = fmaf(v.x, __builtin_amdgcn_rcpf(t + 1.f), a0);
          float y2 = fminf(q.x + l.x, 88.f), t2 = __expf(y2);
          a1 = fmaf(v.x, __builtin_amdgcn_rcpf(t2 + 1.f), a1);
        }
        {
          float y = fminf(q.y + k.y, 88.f), t = __expf(y);
          a0 = fmaf(v.y, __builtin_amdgcn_rcpf(t + 1.f), a0);
          float y2 = fminf(q.y + l.y, 88.f), t2 = __expf(y2);
          a1 = fmaf(v.y, __builtin_amdgcn_rcpf(t2 + 1.f), a1);
        }
        {
          float y = fminf(q.z + k.z, 88.f), t = __expf(y);
          a0 = fmaf(v.z, __builtin_amdgcn_rcpf(t + 1.f), a0);
          float y2 = fminf(q.z + l.z, 88.f), t2 = __expf(y2);
          a1 = fmaf(v.z, __builtin_amdgcn_rcpf(t2 + 1.f), a1);
        }
        {
          float y = fminf(q.w + k.w, 88.f), t = __expf(y);
          a0 = fmaf(v.w, __builtin_amdgcn_rcpf(t + 1.f), a0);
          float y2 = fminf(q.w + l.w, 88.f), t2 = __expf(y2);
          a1 = fmaf(v.w, __builtin_amdgcn_rcpf(t2 + 1.f), a1);
        }
      }
      float u0 = Vsum + a0;      // vp and -2vp split: u = sum vp - 2 sum vp*r
      float u1 = Vsum + a1;
      u0 += __shfl_xor(u0, 1); u0 += __shfl_xor(u0, 2); u0 += __shfl_xor(u0, 4);
      u1 += __shfl_xor(u1, 1); u1 += __shfl_xor(u1, 2); u1 += __shfl_xor(u1, 4);
      if (hc == 0) {
        float lg0 = 10.f * tanhf(u0);
        float lg1 = 10.f * tanhf(u1);
        lg_s[s0] = lg0; val_s[s0] = lg0 + g01.x;
        lg_s[s1] = lg1; val_s[s1] = lg1 + g01.y;
      }
    }
    __syncthreads();                                    // sync1: lg/val ready

    // ---- phase B: per-wave argmax(val) [first-index tiebreak], max(lg), sum exp(lg-ml) ----
    if (tid < NS) {
      float lgl = lg_s[tid];
      float v = val_s[tid]; int vi = tid; float ml = lgl;
      #pragma unroll
      for (int off = 1; off < 64; off <<= 1) {
        float ov = __shfl_xor(v, off);
        int   oi = __shfl_xor(vi, off);
        bool take = (ov > v) || (ov == v && oi < vi);
        v  = take ? ov : v;
        vi = take ? oi : vi;
        ml = fmaxf(ml, __shfl_xor(ml, off));
      }
      float e = __expf(lgl - ml);
      #pragma unroll
      for (int off = 1; off < 64; off <<= 1) e += __shfl_xor(e, off);
      if ((tid & 63) == 0) {
        red_v[tid >> 6] = v; red_i[tid >> 6] = vi;
        red_ml[tid >> 6] = ml; red_e[tid >> 6] = e;
      }
    }
    __syncthreads();                                    // sync2: wave partials ready

    // ---- phase C: ALL threads combine -> idx (no broadcast barrier) ----
    float bvv = red_v[0]; int bii = red_i[0];
    #pragma unroll
    for (int w = 1; w < 4; ++w) {
      bool take = (red_v[w] > bvv) || (red_v[w] == bvv && red_i[w] < bii);
      bvv = take ? red_v[w] : bvv;
      bii = take ? red_i[w] : bii;
    }
    const int idx = bii;

    if (tid == 0) {
      float ml = fmaxf(fmaxf(red_ml[0], red_ml[1]), fmaxf(red_ml[2], red_ml[3]));
      float sum = 0.f;
      #pragma unroll
      for (int w = 0; w < 4; ++w) sum += red_e[w] * __expf(red_ml[w] - ml);
      logp += lg_s[idx] - (ml + logf(sum));
      idx_hist[i] = idx;
      out[2 * NB + b * NM + i] = (float)idx;
    }

    // mask whole 4-node cell of idx (thread covers half a cell; both s go together)
    if (!m && (pr >> 1) == (idx >> 2)) { m = 1; pend = 1; }

    // ---- one-time after step 0: fold Qinit = (emb[idx0]@Wv_top)@Wq into qbase ----
    if (i == 0) {
      if (tid < NE) er[tid] = emb[((size_t)b * NS + idx) * NE + tid];
      __syncthreads();
      if (tid < NE) {
        float tv = 0.f;
        #pragma unroll 4
        for (int j = 0; j < NE; ++j) tv = fmaf(er[j], Wv[j * NE + tid], tv);
        Ts[tid] = tv;
      }
      __syncthreads();
      if (tid < NE) {
        float qi = 0.f;
        #pragma unroll 4
        for (int e2 = 0; e2 < NE; ++e2) qi = fmaf(Ts[e2], Wq[e2 * NH + tid], qi);
        qb_reg += 2.0f * qi;
      }
    }

    // ---- next step's qW = qbase + Qinit + QB[idx]  (x2 pre-scale) ----
    if (tid < NH) qWp[PIDX(tid)] = qb_reg + 2.0f * QB_g[((size_t)b * NS + idx) * NH + tid];
    __syncthreads();                                    // sync3: qW ready for next step
  }

  if (tid == 0) out[b] = logp;

  // ---- deferred reward: one wave, all 63 transition terms in parallel ----
  if (tid < 64) {
    float term = 0.f;
    if (tid > 0) {
      int id = idx_hist[tid];
      int pv = idx_hist[tid - 1];
      float dx = node[((size_t)b * NS + id) * 4 + 0] - node[((size_t)b * NS + pv) * 4 + 2];
      float dy = node[((size_t)b * NS + id) * 4 + 1] - node[((size_t)b * NS + pv) * 4 + 3];
      term = sqrtf(dx * dx + dy * dy) + costs[(size_t)b * NS + pv] + costs[(size_t)b * NS + id];
    }
    #pragma unroll
    for (int off = 1; off < 64; off <<= 1) term += __shfl_xor(term, off);
    if (tid == 0) out[NB + b] = term;
  }
}

extern "C" void kernel_launch(void* const* d_in, const int* in_sizes, int n_in,
                              void* d_out, int out_size, void* d_ws, size_t ws_size,
                              hipStream_t stream) {
  const float* emb    = (const float*)d_in[0];
  const float* node   = (const float*)d_in[1];
  // d_in[2] maze (unused), d_in[3] num_cell (constant 64)
  const float* costs  = (const float*)d_in[4];
  const float* init_w = (const float*)d_in[5];
  const float* Whc    = (const float*)d_in[6];
  const float* bhc    = (const float*)d_in[7];
  const float* Wv     = (const float*)d_in[8];
  const float* bv     = (const float*)d_in[9];
  const float* Wq     = (const float*)d_in[10];
  const float* Wk     = (const float*)d_in[11];
  const float* vptr   = (const float*)d_in[12];
  float* out = (float*)d_out;

  float* ws    = (float*)d_ws;
  float* g     = ws;                       // 16*64*256      = 262144
  float* kp    = g + NB * NM * NS;         // 16*256*256     = 1048576
  float* QB    = kp + (size_t)NB * NS * NH;
  float* tmpB  = QB + (size_t)NB * NS * NH;
  float* qbase = tmpB + (size_t)NB * NS * NE;
  float* q0W   = qbase + NB * NH;          // total ~13.1 MB of ws

  gumbel_kernel<<<NB * NM, 256, 0, stream>>>(g);
  prep_kernel<<<NB, NE, 0, stream>>>(emb, init_w, Whc, bhc, Wv, bv, Wq, qbase, q0W);
  mm_kernel<<<NB * NS / 16, 256, 0, stream>>>(emb, Wk, kp);               // k_proj
  mm_kernel<<<NB * NS / 16, 256, 0, stream>>>(emb, Wv + NE * NE, tmpB);   // emb @ Wv_bot
  mm_kernel<<<NB * NS / 16, 256, 0, stream>>>(tmpB, Wq, QB);              // (emb@Wv_bot)@Wq
  decode_kernel<<<NB, 1024, 0, stream>>>(emb, node, costs, Wv, Wq, vptr,
                                         g, kp, QB, qbase, q0W, out);
}